// Round 4
// baseline (790.810 us; speedup 1.0000x reference)
//
#include <hip/hip_runtime.h>

// Problem: inputs (16, 512, 64, 192) fp32; out (16, 25, 64, 192)
constexpr int Bq = 16, Cc = 256, Hh = 64, Ww = 192, Dd = 25;
constexpr int HW = Hh * Ww;              // 12288 floats (channel stride)
constexpr int BSTRIDE = 2 * Cc * HW;     // batch stride
constexpr int NS = 2;                    // channel slices (split-K x2)
constexpr int CS = Cc / NS;              // 128 channels per slice
constexpr int GC = 4;                    // channels per pipeline group
constexpr int NG = CS / GC;              // 32 groups (even -> clean 2x unroll)
constexpr int ROWP = 24 + Ww;            // 216: 24-float zero pad + row
constexpr size_t PLANE = (size_t)Bq * Dd * Hh * Ww;

// One WAVE per (h, b, slice): 64-thread blocks, NO __syncthreads anywhere.
// All staging/compute hazards are intra-wave -> compiler emits precise
// per-dependency s_waitcnt instead of block-wide vmcnt(0) drains; 8
// independent waves/CU (grid 2048) overlap HBM, LDS and VALU pipes.
// Lanes 0..47 compute 4 w each (aligned ds_read_b128 windows); all 64
// lanes cooperate on staging x2 rows into this wave's private LDS.
__global__ __launch_bounds__(64, 2) void corr_kernel(const float* __restrict__ in,
                                                     float* __restrict__ part) {
  const int t = threadIdx.x;          // 0..63
  const int h = blockIdx.x;           // 0..63
  const int b = blockIdx.y;           // 0..15
  const int s = blockIdx.z;           // 0..1

  __shared__ float x2s[2][GC][ROWP];  // 2 slots x 4 ch x 216 = 6.9 KB (per wave)

  // Zero the 24-float left pads: 2*4*24 = 192 entries, 3 passes of 64 lanes.
#pragma unroll
  for (int i = 0; i < 3; ++i) {
    const int idx  = i * 64 + t;
    const int slot = idx / (GC * 24);
    const int rem  = idx % (GC * 24);
    x2s[slot][rem / 24][rem % 24] = 0.0f;
  }

  const float* x1row = in + (size_t)b * BSTRIDE + (size_t)(s * CS) * HW
                          + (size_t)h * Ww;
  const float* x2row = x1row + (size_t)Cc * HW;

  const bool comp = (t < 48);
  const int  w0   = 4 * t;            // lanes 0..47 own w0..w0+3

  float4 acc[Dd];                     // 100 VGPRs of accumulator
#pragma unroll
  for (int d = 0; d < Dd; ++d) acc[d] = make_float4(0.f, 0.f, 0.f, 0.f);

  // Register rings: x2 staged 2 groups ahead (feeds ds_write), x1 ~2 ahead.
  float  px2[2][GC][3];               // [parity][ch][k]: lane t loads 64k+t
  float4 px1[2][GC];                  // [parity][ch]: float4 at w0

  // Prologue: load groups 0 and 1; stage group 0 into LDS slot 0.
#pragma unroll
  for (int gen = 0; gen < 2; ++gen) {
    const float* b2 = x2row + (size_t)(gen * GC) * HW;
#pragma unroll
    for (int c = 0; c < GC; ++c)
#pragma unroll
      for (int k = 0; k < 3; ++k)
        px2[gen][c][k] = b2[(size_t)c * HW + 64 * k + t];
    if (comp) {
      const float* b1 = x1row + (size_t)(gen * GC) * HW;
#pragma unroll
      for (int c = 0; c < GC; ++c)
        px1[gen][c] = *(const float4*)(b1 + (size_t)c * HW + w0);
    }
  }
#pragma unroll
  for (int c = 0; c < GC; ++c)
#pragma unroll
    for (int k = 0; k < 3; ++k)
      x2s[0][c][24 + 64 * k + t] = px2[0][c][k];

  // STEP(g, GS): GS = g&1 (compile-time). Order per step:
  //  1. ds_write group g+1 (regs px2[1-GS]) into LDS slot 1-GS
  //  2. issue x2 global loads for group g+2 into px2[GS] (slot freed at g-1)
  //  3. compute group g from LDS slot GS with x1 regs px1[GS]
  //  4. issue x1 loads for group g+2 into px1[GS] (after compute: WAR-safe)
#define STEP(g, GS)                                                          \
  {                                                                          \
    if ((g) + 1 < NG) {                                                      \
      _Pragma("unroll")                                                      \
      for (int c = 0; c < GC; ++c)                                           \
        _Pragma("unroll")                                                    \
        for (int k = 0; k < 3; ++k)                                          \
          x2s[1 - (GS)][c][24 + 64 * k + t] = px2[1 - (GS)][c][k];           \
    }                                                                        \
    if ((g) + 2 < NG) {                                                      \
      const float* b2 = x2row + (size_t)(((g) + 2) * GC) * HW;               \
      _Pragma("unroll")                                                      \
      for (int c = 0; c < GC; ++c)                                           \
        _Pragma("unroll")                                                    \
        for (int k = 0; k < 3; ++k)                                          \
          px2[GS][c][k] = b2[(size_t)c * HW + 64 * k + t];                   \
    }                                                                        \
    if (comp) {                                                              \
      _Pragma("unroll")                                                      \
      for (int c = 0; c < GC; ++c) {                                         \
        float win[28];                                                       \
        _Pragma("unroll")                                                    \
        for (int k = 0; k < 7; ++k)                                          \
          *(float4*)&win[4 * k] = *(const float4*)&x2s[GS][c][w0 + 4 * k];   \
        const float4 a = px1[GS][c];                                         \
        _Pragma("unroll")                                                    \
        for (int d = 0; d < Dd; ++d) {                                       \
          acc[d].x = fmaf(a.x, win[24 - d], acc[d].x);                       \
          acc[d].y = fmaf(a.y, win[25 - d], acc[d].y);                       \
          acc[d].z = fmaf(a.z, win[26 - d], acc[d].z);                       \
          acc[d].w = fmaf(a.w, win[27 - d], acc[d].w);                       \
        }                                                                    \
      }                                                                      \
      if ((g) + 2 < NG) {                                                    \
        const float* b1 = x1row + (size_t)(((g) + 2) * GC) * HW;             \
        _Pragma("unroll")                                                    \
        for (int c = 0; c < GC; ++c)                                         \
          px1[GS][c] = *(const float4*)(b1 + (size_t)c * HW + w0);           \
      }                                                                      \
    }                                                                        \
  }

  for (int g = 0; g < NG; g += 2) {
    STEP(g, 0)
    STEP(g + 1, 1)
  }
#undef STEP

  // Epilogue: partial plane (s, b, d, h, w)
  if (comp) {
    float* cp = part + (size_t)s * PLANE + ((size_t)b * Dd * Hh + h) * Ww + w0;
#pragma unroll
    for (int d = 0; d < Dd; ++d)
      *(float4*)(cp + (size_t)d * HW) = acc[d];
  }
}

// Box: slice-sum + 3x3 ones depthwise conv (zero pad). h-marching running
// vertical sum (each partial element read ONCE), horizontal 3-tap via LDS.
__global__ __launch_bounds__(192) void box_kernel(const float* __restrict__ part,
                                                  float* __restrict__ out) {
  const int w    = threadIdx.x;     // 0..191
  const int half = blockIdx.x;      // 0..1 (h halves)
  const int bd   = blockIdx.y;      // 0..399
  const int h0   = half * 32;

  const float* p0 = part + (size_t)bd * Hh * Ww;
  const float* p1 = p0 + PLANE;

  __shared__ float v[Ww + 2];
  if (w == 0) v[0] = 0.f;
  if (w == 1) v[Ww + 1] = 0.f;

  auto loadrow = [&](int hh) -> float {
    if (hh < 0 || hh >= Hh) return 0.f;
    return p0[(size_t)hh * Ww + w] + p1[(size_t)hh * Ww + w];
  };

  float rp = loadrow(h0 - 1);
  float rc = loadrow(h0);
  for (int h = h0; h < h0 + 32; ++h) {
    const float rn = loadrow(h + 1);
    __syncthreads();                 // previous iteration's v reads complete
    v[w + 1] = rp + rc + rn;
    __syncthreads();
    out[((size_t)bd * Hh + h) * Ww + w] = v[w] + v[w + 1] + v[w + 2];
    rp = rc; rc = rn;
  }
}

extern "C" void kernel_launch(void* const* d_in, const int* in_sizes, int n_in,
                              void* d_out, int out_size, void* d_ws, size_t ws_size,
                              hipStream_t stream) {
  const float* in = (const float*)d_in[0];
  float* out  = (float*)d_out;
  float* part = (float*)d_ws;        // 2 x 19.66 MB partials, fully overwritten

  dim3 g1(Hh, Bq, NS);               // (64, 16, 2) = 2048 single-wave blocks
  corr_kernel<<<g1, 64, 0, stream>>>(in, part);

  dim3 g2(2, Bq * Dd);               // (2, 400)
  box_kernel<<<g2, 192, 0, stream>>>(part, out);
}